// Round 2
// baseline (1241.168 us; speedup 1.0000x reference)
//
#include <hip/hip_runtime.h>
#include <stdint.h>

#define DIM 128
#define LN_EPS 1e-5f

static __device__ __forceinline__ float rlane(float v, int lane) {
    return __uint_as_float(
        (uint32_t)__builtin_amdgcn_readlane((int)__float_as_uint(v), lane));
}

// ---------------------------------------------------------------------------
// K1: edge scatter — mean-aggregation numerator + counts. fp32 everywhere.
// 32 lanes per edge; each lane loads one float4 (16B) of x[src] and does
// 4 fp32 atomicAdds into agg[dst].
// ---------------------------------------------------------------------------
__global__ __launch_bounds__(256) void scatter_kernel(
    const float* __restrict__ x,
    const int* __restrict__ ei,
    float* __restrict__ agg,
    float* __restrict__ cnt,
    int E)
{
    int gid = blockIdx.x * blockDim.x + threadIdx.x;
    int e = gid >> 5;
    if (e >= E) return;
    int c = gid & 31;

    int src = ei[e];
    int dst = ei[E + e];

    const float4* xrow = (const float4*)(x + (size_t)src * DIM);
    float4 v = xrow[c];

    float* dp = agg + (size_t)dst * DIM + c * 4;
    atomicAdd(dp + 0, v.x);
    atomicAdd(dp + 1, v.y);
    atomicAdd(dp + 2, v.z);
    atomicAdd(dp + 3, v.w);

    if (c == 0) atomicAdd(cnt + dst, 1.0f);
}

// ---------------------------------------------------------------------------
// K2: fused  h = mean @ W_l^T + b_l + x @ W_r^T ; LayerNorm ; ReLU  (fp32)
// One wave handles 8 rows. Lane l owns output features {l, l+64}.
// a-vector (mean || x, 256 values) distributed across lanes (av[r][j] holds
// a[j*64 + lane]), broadcast per-k via v_readlane; W rows streamed per-lane
// with float4 loads (W set = 128 KB, L2 resident).
// ---------------------------------------------------------------------------
__global__ __launch_bounds__(256) void fused_kernel(
    const float* __restrict__ x,
    const float* __restrict__ agg,
    const float* __restrict__ cnt,
    const float* __restrict__ Wl,
    const float* __restrict__ bl,
    const float* __restrict__ Wr,
    const float* __restrict__ gma,
    const float* __restrict__ bta,
    float* __restrict__ out,
    int N)
{
    const int lane = threadIdx.x & 63;
    const int wave = blockIdx.x * (blockDim.x >> 6) + (threadIdx.x >> 6);
    const int row0 = wave * 8;
    if (row0 >= N) return;

    // av[r][j] = a_row[j*64 + lane];  a = concat(mean, x), length 256
    float av[8][4];
    #pragma unroll
    for (int r = 0; r < 8; ++r) {
        int row = row0 + r;
        int rr = (row < N) ? row : 0;
        float c = cnt[rr];
        float rc = 1.0f / fmaxf(c, 1.0f);
        const float* ag = agg + (size_t)rr * DIM;
        const float* xr = x + (size_t)rr * DIM;
        float m0 = ag[lane] * rc;
        float m1 = ag[lane + 64] * rc;
        float x0 = xr[lane];
        float x1 = xr[lane + 64];
        bool ok = (row < N);
        av[r][0] = ok ? m0 : 0.0f;
        av[r][1] = ok ? m1 : 0.0f;
        av[r][2] = ok ? x0 : 0.0f;
        av[r][3] = ok ? x1 : 0.0f;
    }

    const float bl0 = bl[lane];
    const float bl1 = bl[lane + 64];
    float acc0[8], acc1[8];
    #pragma unroll
    for (int r = 0; r < 8; ++r) { acc0[r] = bl0; acc1[r] = bl1; }

    const int d = lane;
    #pragma unroll
    for (int j = 0; j < 4; ++j) {
        const float* Wb = (j < 2) ? Wl : Wr;
        const float4* p0 = (const float4*)(Wb + (size_t)d * DIM + (j & 1) * 64);
        const float4* p1 = (const float4*)(Wb + (size_t)(d + 64) * DIM + (j & 1) * 64);
        #pragma unroll 4
        for (int q = 0; q < 16; ++q) {
            float4 w0 = p0[q];
            float4 w1 = p1[q];
            int kb = q * 4;
            #pragma unroll
            for (int r = 0; r < 8; ++r) {
                float a0 = rlane(av[r][j], kb + 0);
                float a1 = rlane(av[r][j], kb + 1);
                float a2 = rlane(av[r][j], kb + 2);
                float a3 = rlane(av[r][j], kb + 3);
                acc0[r] = fmaf(a0, w0.x, acc0[r]);
                acc1[r] = fmaf(a0, w1.x, acc1[r]);
                acc0[r] = fmaf(a1, w0.y, acc0[r]);
                acc1[r] = fmaf(a1, w1.y, acc1[r]);
                acc0[r] = fmaf(a2, w0.z, acc0[r]);
                acc1[r] = fmaf(a2, w1.z, acc1[r]);
                acc0[r] = fmaf(a3, w0.w, acc0[r]);
                acc1[r] = fmaf(a3, w1.w, acc1[r]);
            }
        }
    }

    const float g0 = gma[lane];
    const float g1 = gma[lane + 64];
    const float be0 = bta[lane];
    const float be1 = bta[lane + 64];

    #pragma unroll
    for (int r = 0; r < 8; ++r) {
        int row = row0 + r;
        if (row >= N) break;                       // wave-uniform
        float h0 = acc0[r], h1 = acc1[r];
        float s = h0 + h1;
        float q = h0 * h0 + h1 * h1;
        #pragma unroll
        for (int off = 32; off > 0; off >>= 1) {
            s += __shfl_xor(s, off, 64);
            q += __shfl_xor(q, off, 64);
        }
        float mu = s * (1.0f / 128.0f);
        float var = q * (1.0f / 128.0f) - mu * mu;
        float rs = rsqrtf(fmaxf(var, 0.0f) + LN_EPS);
        float o0 = fmaxf((h0 - mu) * rs * g0 + be0, 0.0f);
        float o1 = fmaxf((h1 - mu) * rs * g1 + be1, 0.0f);
        out[(size_t)row * DIM + lane] = o0;
        out[(size_t)row * DIM + lane + 64] = o1;
    }
}

extern "C" void kernel_launch(void* const* d_in, const int* in_sizes, int n_in,
                              void* d_out, int out_size, void* d_ws, size_t ws_size,
                              hipStream_t stream) {
    const float* x  = (const float*)d_in[0];
    const int* ei   = (const int*)d_in[1];
    const float* Wl = (const float*)d_in[2];
    const float* bl = (const float*)d_in[3];
    const float* Wr = (const float*)d_in[4];
    const float* ga = (const float*)d_in[5];
    const float* be = (const float*)d_in[6];
    float* out = (float*)d_out;

    int N = in_sizes[0] / DIM;   // 50000
    int E = in_sizes[1] / 2;     // 600000

    float* agg = (float*)d_ws;
    float* cnt = agg + (size_t)N * DIM;

    hipMemsetAsync(d_ws, 0, ((size_t)N * DIM + (size_t)N) * sizeof(float), stream);

    {
        long long threads = (long long)E * 32;
        int blocks = (int)((threads + 255) / 256);
        scatter_kernel<<<blocks, 256, 0, stream>>>(x, ei, agg, cnt, E);
    }
    {
        int waves = (N + 7) / 8;
        int blocks = (waves + 3) / 4;
        fused_kernel<<<blocks, 256, 0, stream>>>(x, agg, cnt, Wl, bl, Wr, ga, be, out, N);
    }
}

// Round 3
// 332.269 us; speedup vs baseline: 3.7354x; 3.7354x over previous
//
#include <hip/hip_runtime.h>
#include <stdint.h>

#define DIM 128
#define LN_EPS 1e-5f
#define SCAN_B 1024

static __device__ __forceinline__ float rlane(float v, int lane) {
    return __uint_as_float(
        (uint32_t)__builtin_amdgcn_readlane((int)__float_as_uint(v), lane));
}

// ---------------------------------------------------------------------------
// K1: per-destination degree count. 600k int atomics over 50k counters.
// ---------------------------------------------------------------------------
__global__ __launch_bounds__(256) void degree_kernel(
    const int* __restrict__ ei, int* __restrict__ deg, int E)
{
    int e = blockIdx.x * blockDim.x + threadIdx.x;
    if (e >= E) return;
    atomicAdd(deg + ei[E + e], 1);
}

// ---------------------------------------------------------------------------
// K2a: block-wise exclusive scan of deg -> offs (block-local), block totals.
// ---------------------------------------------------------------------------
__global__ __launch_bounds__(SCAN_B) void scan1_kernel(
    const int* __restrict__ deg, int* __restrict__ offs,
    int* __restrict__ totals, int N)
{
    __shared__ int lds[SCAN_B];
    int t = threadIdx.x, b = blockIdx.x;
    int i = b * SCAN_B + t;
    int v = (i < N) ? deg[i] : 0;
    lds[t] = v;
    __syncthreads();
    #pragma unroll
    for (int d = 1; d < SCAN_B; d <<= 1) {
        int u = (t >= d) ? lds[t - d] : 0;
        __syncthreads();
        lds[t] += u;
        __syncthreads();
    }
    int incl = lds[t];
    if (i < N) offs[i] = incl - v;          // exclusive within block
    if (t == SCAN_B - 1) totals[b] = incl;  // block total
}

// ---------------------------------------------------------------------------
// K2b: add block bases (serial over <=49 totals, redundant per thread),
// finalize offs and copy to cursor.
// ---------------------------------------------------------------------------
__global__ __launch_bounds__(SCAN_B) void scan2_kernel(
    int* __restrict__ offs, const int* __restrict__ totals,
    int* __restrict__ cursor, int N)
{
    int t = threadIdx.x, b = blockIdx.x;
    int base = 0;
    for (int j = 0; j < b; ++j) base += totals[j];
    int i = b * SCAN_B + t;
    if (i < N) {
        int o = offs[i] + base;
        offs[i] = o;
        cursor[i] = o;
    }
}

// ---------------------------------------------------------------------------
// K3: fill CSR edge lists via ticketed cursor.
// ---------------------------------------------------------------------------
__global__ __launch_bounds__(256) void fill_kernel(
    const int* __restrict__ ei, int* __restrict__ cursor,
    int* __restrict__ src_list, int E)
{
    int e = blockIdx.x * blockDim.x + threadIdx.x;
    if (e >= E) return;
    int src = ei[e];
    int dst = ei[E + e];
    int p = atomicAdd(cursor + dst, 1);
    src_list[p] = src;
}

// ---------------------------------------------------------------------------
// K4: fused  mean-gather ; h = mean@W_l^T + b_l + x@W_r^T ; LayerNorm ; ReLU
// One wave per 8 rows. Lane l owns output features {l, l+64}. The mean is
// gathered directly into the distributed register layout (no atomics, no
// mean buffer): for each neighbor s, lanes read x[s*128 + lane] and
// x[s*128 + 64 + lane] (coalesced 256B wave-loads, LLC-resident).
// ---------------------------------------------------------------------------
__global__ __launch_bounds__(256) void fused_kernel(
    const float* __restrict__ x,
    const int* __restrict__ offs,
    const int* __restrict__ deg,
    const int* __restrict__ src_list,
    const float* __restrict__ Wl,
    const float* __restrict__ bl,
    const float* __restrict__ Wr,
    const float* __restrict__ gma,
    const float* __restrict__ bta,
    float* __restrict__ out,
    int N)
{
    const int lane = threadIdx.x & 63;
    const int wave = blockIdx.x * (blockDim.x >> 6) + (threadIdx.x >> 6);
    const int row0 = wave * 8;
    if (row0 >= N) return;

    // av[r][j] = a_row[j*64 + lane];  a = concat(mean, x), length 256
    float av[8][4];
    #pragma unroll
    for (int r = 0; r < 8; ++r) {
        int row = row0 + r;
        bool ok = (row < N);
        int rr = ok ? row : 0;
        int off = __builtin_amdgcn_readfirstlane(offs[rr]);
        int dg  = ok ? __builtin_amdgcn_readfirstlane(deg[rr]) : 0;

        float m0 = 0.0f, m1 = 0.0f;
        for (int bbase = 0; bbase < dg; bbase += 64) {
            int nn = dg - bbase; if (nn > 64) nn = 64;
            int sidx = (lane < nn) ? src_list[off + bbase + lane] : 0;
            for (int j = 0; j < nn; ++j) {
                int s = __builtin_amdgcn_readlane(sidx, j);
                const float* xr = x + (size_t)s * DIM;
                m0 += xr[lane];
                m1 += xr[lane + 64];
            }
        }
        float rc = (dg > 0) ? (1.0f / (float)dg) : 0.0f;
        const float* xw = x + (size_t)rr * DIM;
        av[r][0] = m0 * rc;
        av[r][1] = m1 * rc;
        av[r][2] = ok ? xw[lane] : 0.0f;
        av[r][3] = ok ? xw[lane + 64] : 0.0f;
    }

    const float bl0 = bl[lane];
    const float bl1 = bl[lane + 64];
    float acc0[8], acc1[8];
    #pragma unroll
    for (int r = 0; r < 8; ++r) { acc0[r] = bl0; acc1[r] = bl1; }

    const int d = lane;
    #pragma unroll
    for (int j = 0; j < 4; ++j) {
        const float* Wb = (j < 2) ? Wl : Wr;
        const float4* p0 = (const float4*)(Wb + (size_t)d * DIM + (j & 1) * 64);
        const float4* p1 = (const float4*)(Wb + (size_t)(d + 64) * DIM + (j & 1) * 64);
        #pragma unroll 4
        for (int q = 0; q < 16; ++q) {
            float4 w0 = p0[q];
            float4 w1 = p1[q];
            int kb = q * 4;
            #pragma unroll
            for (int r = 0; r < 8; ++r) {
                float a0 = rlane(av[r][j], kb + 0);
                float a1 = rlane(av[r][j], kb + 1);
                float a2 = rlane(av[r][j], kb + 2);
                float a3 = rlane(av[r][j], kb + 3);
                acc0[r] = fmaf(a0, w0.x, acc0[r]);
                acc1[r] = fmaf(a0, w1.x, acc1[r]);
                acc0[r] = fmaf(a1, w0.y, acc0[r]);
                acc1[r] = fmaf(a1, w1.y, acc1[r]);
                acc0[r] = fmaf(a2, w0.z, acc0[r]);
                acc1[r] = fmaf(a2, w1.z, acc1[r]);
                acc0[r] = fmaf(a3, w0.w, acc0[r]);
                acc1[r] = fmaf(a3, w1.w, acc1[r]);
            }
        }
    }

    const float g0 = gma[lane];
    const float g1 = gma[lane + 64];
    const float be0 = bta[lane];
    const float be1 = bta[lane + 64];

    #pragma unroll
    for (int r = 0; r < 8; ++r) {
        int row = row0 + r;
        if (row >= N) break;                       // wave-uniform
        float h0 = acc0[r], h1 = acc1[r];
        float s = h0 + h1;
        float q = h0 * h0 + h1 * h1;
        #pragma unroll
        for (int off = 32; off > 0; off >>= 1) {
            s += __shfl_xor(s, off, 64);
            q += __shfl_xor(q, off, 64);
        }
        float mu = s * (1.0f / 128.0f);
        float var = q * (1.0f / 128.0f) - mu * mu;
        float rs = rsqrtf(fmaxf(var, 0.0f) + LN_EPS);
        float o0 = fmaxf((h0 - mu) * rs * g0 + be0, 0.0f);
        float o1 = fmaxf((h1 - mu) * rs * g1 + be1, 0.0f);
        out[(size_t)row * DIM + lane] = o0;
        out[(size_t)row * DIM + lane + 64] = o1;
    }
}

extern "C" void kernel_launch(void* const* d_in, const int* in_sizes, int n_in,
                              void* d_out, int out_size, void* d_ws, size_t ws_size,
                              hipStream_t stream) {
    const float* x  = (const float*)d_in[0];
    const int* ei   = (const int*)d_in[1];
    const float* Wl = (const float*)d_in[2];
    const float* bl = (const float*)d_in[3];
    const float* Wr = (const float*)d_in[4];
    const float* ga = (const float*)d_in[5];
    const float* be = (const float*)d_in[6];
    float* out = (float*)d_out;

    int N = in_sizes[0] / DIM;   // 50000
    int E = in_sizes[1] / 2;     // 600000
    int nb = (N + SCAN_B - 1) / SCAN_B;

    int* deg      = (int*)d_ws;
    int* offs     = deg + N;
    int* cursor   = offs + N;
    int* totals   = cursor + N;
    int* src_list = totals + ((nb + 63) & ~63);

    hipMemsetAsync(deg, 0, (size_t)N * sizeof(int), stream);

    degree_kernel<<<(E + 255) / 256, 256, 0, stream>>>(ei, deg, E);
    scan1_kernel<<<nb, SCAN_B, 0, stream>>>(deg, offs, totals, N);
    scan2_kernel<<<nb, SCAN_B, 0, stream>>>(offs, totals, cursor, N);
    fill_kernel<<<(E + 255) / 256, 256, 0, stream>>>(ei, cursor, src_list, E);

    {
        int waves = (N + 7) / 8;
        int blocks = (waves + 3) / 4;
        fused_kernel<<<blocks, 256, 0, stream>>>(x, offs, deg, src_list,
                                                 Wl, bl, Wr, ga, be, out, N);
    }
}